// Round 3
// baseline (952.268 us; speedup 1.0000x reference)
//
#include <hip/hip_runtime.h>

#define BS 1024
#define TS 64
#define HID 64
#define NG 256

__device__ __forceinline__ float sigf_p(float x){ return 1.f/(1.f+expf(-x)); }
__device__ __forceinline__ float sigf(float x){ return 1.f/(1.f+__expf(-x)); }
__device__ __forceinline__ float tanh_fast(float x){
  float cx = fminf(fmaxf(x,-15.f),15.f);
  float e = __expf(2.f*cx);
  return (e-1.f)/(e+1.f);
}
__device__ __forceinline__ float lrelu(float v){ return v>=0.f ? v : 0.1f*v; }
__device__ __forceinline__ float dot4(float4 a, float4 b){
  return a.x*b.x + a.y*b.y + a.z*b.z + a.w*b.w;
}

// ---------------- Kernel A: batch-independent precompute (unchanged, correct) ----------------
__global__ __launch_bounds__(256) void precompute_kernel(
    const float* __restrict__ Whh_t, const float* __restrict__ bih_t,
    const float* __restrict__ bhh_t,
    const float* __restrict__ Wof,  const float* __restrict__ bof,
    const float* __restrict__ Wtf,  const float* __restrict__ btf,
    const float* __restrict__ Wmix, const float* __restrict__ bmix,
    float* __restrict__ ws_wcomb, float* __restrict__ ws_mbias)
{
  __shared__ __align__(16) float4 sWtfT[16*64];
  __shared__ __align__(16) float4 sWm1T[16*64];
  __shared__ float sWof[64*64];
  __shared__ float sBof[64];
  __shared__ __align__(16) float sH[64];
  __shared__ __align__(16) float sTs[64];
  __shared__ float sG[256];

  const int t = threadIdx.x;

  float4 wv[16];
#pragma unroll
  for (int j4=0;j4<16;++j4) wv[j4] = reinterpret_cast<const float4*>(Whh_t + t*64)[j4];
  const float btr = bih_t[t] + bhh_t[t];

  for (int i=t;i<64*64;i+=256) sWof[i] = Wof[i];
  if (t<64){
    sBof[t] = bof[t];
    sH[t]   = 0.f;
#pragma unroll
    for (int j4=0;j4<16;++j4){
      sWtfT[j4*64+t] = reinterpret_cast<const float4*>(Wtf  + t*64 )[j4];
      sWm1T[j4*64+t] = reinterpret_cast<const float4*>(Wmix + t*128)[j4];
    }
  }
  __syncthreads();

  float cmr = 0.f, btfr = 0.f;
  if (t<64){
    btfr = btf[t];
    float acc = bmix[t];
    for (int k=0;k<64;++k) acc += Wmix[t*128+64+k]*sBof[k];
    cmr = acc;
  }
  for (int i=0;i<16;++i){
    int o = i*256+t;
    int r = o>>6, j = o&63;
    float acc = 0.f;
    for (int k=0;k<64;++k) acc += Wmix[r*128+64+k]*sWof[k*64+j];
    ws_wcomb[o] = acc;
  }

  float c_reg = 0.f;
  const float4* sH4  = reinterpret_cast<const float4*>(sH);
  const float4* sTs4 = reinterpret_cast<const float4*>(sTs);

  for (int s=0; s<TS; ++s){
    float acc = btr;
#pragma unroll
    for (int j4=0;j4<16;++j4) acc += dot4(wv[j4], sH4[j4]);
    sG[t] = acc;
    __syncthreads();
    if (t<64){
      float ig = sigf_p(sG[t]);
      float fg = sigf_p(sG[64+t]);
      float gg = tanhf(sG[128+t]);
      float og = sigf_p(sG[192+t]);
      c_reg = fg*c_reg + ig*gg;
      sH[t] = og*tanhf(c_reg);
    }
    __syncthreads();
    if (t<64){
      float a2 = btfr;
#pragma unroll
      for (int j4=0;j4<16;++j4) a2 += dot4(sWtfT[j4*64+t], sH4[j4]);
      sTs[t] = a2;
    }
    __syncthreads();
    if (t<64){
      float a3 = cmr;
#pragma unroll
      for (int j4=0;j4<16;++j4) a3 += dot4(sWm1T[j4*64+t], sTs4[j4]);
      ws_mbias[s*64+t] = a3;
    }
    __syncthreads();
  }
}

// ---------------- Kernel B: one wave per batch element ----------------
__global__ __launch_bounds__(64,1) void main_kernel(
    const float* __restrict__ obsv,
    const float* __restrict__ Wih_o, const float* __restrict__ Whh_o,
    const float* __restrict__ bih_o, const float* __restrict__ bhh_o,
    const float* __restrict__ W1, const float* __restrict__ b1,
    const float* __restrict__ W2, const float* __restrict__ b2,
    const float* __restrict__ W3, const float* __restrict__ b3,
    const float* __restrict__ wcomb, const float* __restrict__ mbias,
    float* __restrict__ out)
{
  __shared__ __align__(16) float4 sWc[16*64];   // Wcomb transposed-packed (16 KB)
  __shared__ __align__(16) float sH[64];
  __shared__ __align__(16) float sM[64];
  __shared__ __align__(16) float sA1[32];
  __shared__ float sObs[16];
  __shared__ float sBuf[6];     // [slot(3)][r(2)]

  const int k    = threadIdx.x;     // 0..63 (one wave)
  const int blk  = blockIdx.x;      // batch element
  const int rr   = k & 31;
  const int half = k >> 5;

  // c_out zero region: floats [BS*TS*2, BS*TS*3)
  out[BS*TS*2 + blk*64 + k] = 0.f;

  // ---- weights into registers ----
  float4 wv[4][16];                 // Whh_o rows k, 64+k, 128+k, 192+k
#pragma unroll
  for (int g=0; g<4; ++g){
    const float4* row = reinterpret_cast<const float4*>(Whh_o + (g*64+k)*64);
#pragma unroll
    for (int j=0;j<16;++j) wv[g][j] = row[j];
  }
  float wi0[4], wi1[4], bo4[4];
#pragma unroll
  for (int g=0; g<4; ++g){
    wi0[g] = Wih_o[(g*64+k)*2];
    wi1[g] = Wih_o[(g*64+k)*2+1];
    bo4[g] = bih_o[g*64+k] + bhh_o[g*64+k];
  }
  float4 w1p[8];                    // W1 row rr, half `half`
#pragma unroll
  for (int j=0;j<8;++j) w1p[j] = reinterpret_cast<const float4*>(W1 + rr*64 + half*32)[j];
  float4 w2p[4];                    // W2 row rr, half `half`
#pragma unroll
  for (int j=0;j<4;++j) w2p[j] = reinterpret_cast<const float4*>(W2 + rr*32 + half*16)[j];
  const float b1r  = b1[rr];
  const float b2r  = b2[rr];
  const float w3c0 = W3[rr];        // W3 row 0, col rr
  const float w3c1 = W3[32+rr];     // W3 row 1, col rr
  const float b3r  = b3[k&1];

  // ---- LDS staging ----
#pragma unroll
  for (int j=0;j<16;++j)
    sWc[j*64+k] = reinterpret_cast<const float4*>(wcomb + k*64)[j];
  if (k<16) sObs[k] = obsv[blk*16+k];
  if (k<6)  sBuf[k] = obsv[blk*16+10+k];   // obsv[:,5:8,:]
  __syncthreads();

  float4 hv[16];
#pragma unroll
  for (int j=0;j<16;++j) hv[j] = make_float4(0.f,0.f,0.f,0.f);
  float c_reg = 0.f;

  const float4* sH4  = reinterpret_cast<const float4*>(sH);
  const float4* sM4  = reinterpret_cast<const float4*>(sM);
  const float4* sA14 = reinterpret_cast<const float4*>(sA1);

  // ---- warmup: 8 obsv LSTM steps ----
  for (int s=0;s<8;++s){
    const float x0 = sObs[2*s], x1 = sObs[2*s+1];
    float acc[4];
#pragma unroll
    for (int g=0;g<4;++g) acc[g] = bo4[g] + wi0[g]*x0 + wi1[g]*x1;
#pragma unroll
    for (int j=0;j<16;++j){
      const float4 h4 = hv[j];
#pragma unroll
      for (int g=0;g<4;++g) acc[g] += dot4(wv[g][j], h4);
    }
    c_reg = sigf(acc[1])*c_reg + sigf(acc[0])*tanh_fast(acc[2]);
    sH[k] = sigf(acc[3])*tanh_fast(c_reg);
    __syncthreads();
#pragma unroll
    for (int j=0;j<16;++j) hv[j] = sH4[j];
  }

  // ---- main loop: 64 output steps ----
  for (int step=0; step<TS; ++step){
    const float mbg = mbias[step*64+k];   // hidden under gate FMAs
    if (step>0){
      const float x0 = sBuf[4], x1 = sBuf[5];   // prev y
      float acc[4];
#pragma unroll
      for (int g=0;g<4;++g) acc[g] = bo4[g] + wi0[g]*x0 + wi1[g]*x1;
#pragma unroll
      for (int j=0;j<16;++j){
        const float4 h4 = hv[j];
#pragma unroll
        for (int g=0;g<4;++g) acc[g] += dot4(wv[g][j], h4);
      }
      c_reg = sigf(acc[1])*c_reg + sigf(acc[0])*tanh_fast(acc[2]);
      sH[k] = sigf(acc[3])*tanh_fast(c_reg);
      __syncthreads();
#pragma unroll
      for (int j=0;j<16;++j) hv[j] = sH4[j];
    }

    // mix: m[k] = Wcomb[k,:] @ h + mbias[step][k]
    float accm = mbg;
#pragma unroll
    for (int j=0;j<16;++j) accm += dot4(sWc[j*64+k], hv[j]);
    sM[k] = accm;
    __syncthreads();

    // MLP1 (32x64): split-K across wave halves
    float a1acc = 0.f;
#pragma unroll
    for (int jj=0;jj<8;++jj) a1acc += dot4(w1p[jj], sM4[half*8+jj]);
    a1acc += __shfl_xor(a1acc, 32);
    if (k<32) sA1[k] = lrelu(a1acc + b1r);
    __syncthreads();

    // MLP2 (32x32): split-K across wave halves
    float a2acc = 0.f;
#pragma unroll
    for (int jj=0;jj<4;++jj) a2acc += dot4(w2p[jj], sA14[half*4+jj]);
    a2acc += __shfl_xor(a2acc, 32);
    const float a2 = lrelu(a2acc + b2r);  // valid on lanes<32

    // output head (2x32): in-register shuffle reduction over lanes 0..31
    float p0 = a2*w3c0, p1 = a2*w3c1;
#pragma unroll
    for (int m=1; m<=16; m<<=1){
      p0 += __shfl_xor(p0, m);
      p1 += __shfl_xor(p1, m);
    }
    if (k<2){
      const float bl0 = sBuf[k];
      const float bl1 = sBuf[2+k];
      const float bl2 = sBuf[4+k];
      const float y = ((k==0)?p0:p1) + b3r + bl2 + (bl2-bl0)*0.5f;
      sBuf[k]   = bl1;
      sBuf[2+k] = bl2;
      sBuf[4+k] = y;
      out[(size_t)(blk*TS+step)*2 + k] = y;
    }
    __syncthreads();
  }
}

extern "C" void kernel_launch(void* const* d_in, const int* in_sizes, int n_in,
                              void* d_out, int out_size, void* d_ws, size_t ws_size,
                              hipStream_t stream)
{
  const float* obsv  = (const float*)d_in[0];
  // d_in[1] = teom : values never used (teom-LSTM input is zeros)
  const float* Wih_o = (const float*)d_in[2];
  const float* Whh_o = (const float*)d_in[3];
  const float* bih_o = (const float*)d_in[4];
  const float* bhh_o = (const float*)d_in[5];
  // d_in[6] = Wih_t : multiplies zeros, unused
  const float* Whh_t = (const float*)d_in[7];
  const float* bih_t = (const float*)d_in[8];
  const float* bhh_t = (const float*)d_in[9];
  const float* Wof   = (const float*)d_in[10];
  const float* bof   = (const float*)d_in[11];
  const float* Wtf   = (const float*)d_in[12];
  const float* btf   = (const float*)d_in[13];
  const float* Wmix  = (const float*)d_in[14];
  const float* bmix  = (const float*)d_in[15];
  const float* W1    = (const float*)d_in[16];
  const float* b1    = (const float*)d_in[17];
  const float* W2    = (const float*)d_in[18];
  const float* b2    = (const float*)d_in[19];
  const float* W3    = (const float*)d_in[20];
  const float* b3    = (const float*)d_in[21];

  float* wsf = (float*)d_ws;   // [0,4096): Wcomb   [4096,8192): mbias

  precompute_kernel<<<1,256,0,stream>>>(Whh_t,bih_t,bhh_t,Wof,bof,Wtf,btf,
                                        Wmix,bmix, wsf, wsf+4096);
  main_kernel<<<BS,64,0,stream>>>(obsv,Wih_o,Whh_o,bih_o,bhh_o,
                                  W1,b1,W2,b2,W3,b3,
                                  wsf, wsf+4096,
                                  (float*)d_out);
}

// Round 4
// 703.416 us; speedup vs baseline: 1.3538x; 1.3538x over previous
//
#include <hip/hip_runtime.h>

#define BS 1024
#define TS 64
#define HID 64

__device__ __forceinline__ float sigf_p(float x){ return 1.f/(1.f+expf(-x)); }
__device__ __forceinline__ float sigf(float x){ return 1.f/(1.f+__expf(-x)); }
__device__ __forceinline__ float tanh_fast(float x){
  float cx = fminf(fmaxf(x,-15.f),15.f);
  float e = __expf(2.f*cx);
  return (e-1.f)/(e+1.f);
}
__device__ __forceinline__ float lrelu(float v){ return v>=0.f ? v : 0.1f*v; }
__device__ __forceinline__ float dot4(float4 a, float4 b){
  return a.x*b.x + a.y*b.y + a.z*b.z + a.w*b.w;
}

// ---------------- Kernel A: batch-independent precompute ----------------
// ws_wcomb[64*64] = Wmix[:,64:] @ Wof
// ws_mbias[TS*64] : per-step mix bias (teom LSTM + Wtf + Wmix1 folded)
__global__ __launch_bounds__(256) void precompute_kernel(
    const float* __restrict__ Whh_t, const float* __restrict__ bih_t,
    const float* __restrict__ bhh_t,
    const float* __restrict__ Wof,  const float* __restrict__ bof,
    const float* __restrict__ Wtf,  const float* __restrict__ btf,
    const float* __restrict__ Wmix, const float* __restrict__ bmix,
    float* __restrict__ ws_wcomb, float* __restrict__ ws_mbias)
{
  __shared__ __align__(16) float sHall[TS*64];   // teom h history
  __shared__ __align__(16) float sTs[TS*64];
  __shared__ float sWof[64*64];
  __shared__ float sG[256];
  __shared__ float sBof[64];
  __shared__ float sCmr[64];

  const int t = threadIdx.x;

  float4 wrow[16];
#pragma unroll
  for (int j=0;j<16;++j) wrow[j] = reinterpret_cast<const float4*>(Whh_t + t*64)[j];
  const float btr = bih_t[t] + bhh_t[t];

  for (int i=t;i<4096;i+=256) sWof[i] = Wof[i];
  if (t<64) sBof[t] = bof[t];
  __syncthreads();

  // ---- serial teom LSTM (z input == 0) ----
  float c_reg = 0.f;
  for (int s=0;s<TS;++s){
    float a0=btr, a1=0.f, a2=0.f, a3=0.f;
    if (s>0){
      const float4* h4 = reinterpret_cast<const float4*>(sHall + (s-1)*64);
#pragma unroll
      for (int j=0;j<16;j+=4){
        a0 += dot4(wrow[j],   h4[j]);
        a1 += dot4(wrow[j+1], h4[j+1]);
        a2 += dot4(wrow[j+2], h4[j+2]);
        a3 += dot4(wrow[j+3], h4[j+3]);
      }
    }
    sG[t] = (a0+a1)+(a2+a3);
    __syncthreads();
    if (t<64){
      float gi=sG[t], gf=sG[64+t], gg=sG[128+t], go=sG[192+t];
      c_reg = sigf_p(gf)*c_reg + sigf_p(gi)*tanhf(gg);
      sHall[s*64+t] = sigf_p(go)*tanhf(c_reg);
    }
    __syncthreads();
  }

  // ---- parallel phase ----
  if (t<64){
    float acc = bmix[t];
    for (int k=0;k<64;++k) acc += Wmix[t*128+64+k]*sBof[k];
    sCmr[t] = acc;                 // Wmix2 @ bof + bmix
  }
  for (int o=t;o<TS*64;o+=256){    // ts_ = h @ Wtf.T + btf
    int s=o>>6, i=o&63;
    float acc = btf[i];
    for (int k=0;k<64;++k) acc += Wtf[i*64+k]*sHall[s*64+k];
    sTs[o] = acc;
  }
  for (int o=t;o<4096;o+=256){     // wcomb = Wmix2 @ Wof
    int r=o>>6, j=o&63;
    float acc = 0.f;
    for (int k=0;k<64;++k) acc += Wmix[r*128+64+k]*sWof[k*64+j];
    ws_wcomb[o] = acc;
  }
  __syncthreads();
  for (int o=t;o<TS*64;o+=256){    // mbias = ts_ @ Wmix1.T + cmr
    int s=o>>6, j=o&63;
    float acc = sCmr[j];
    for (int k=0;k<64;++k) acc += Wmix[j*128+k]*sTs[s*64+k];
    ws_mbias[o] = acc;
  }
}

// ---------------- Kernel B: 1 batch/block, 256 threads, wave0 serial chain ----------------
__global__ __launch_bounds__(256) void main_kernel(
    const float* __restrict__ obsv,
    const float* __restrict__ Wih_o, const float* __restrict__ Whh_o,
    const float* __restrict__ bih_o, const float* __restrict__ bhh_o,
    const float* __restrict__ W1, const float* __restrict__ b1,
    const float* __restrict__ W2, const float* __restrict__ b2,
    const float* __restrict__ W3, const float* __restrict__ b3,
    const float* __restrict__ wcomb, const float* __restrict__ mbias,
    float* __restrict__ out)
{
  __shared__ __align__(16) float4 sWc[16*64];  // 16 KB
  __shared__ __align__(16) float4 sW1[16*32];  // 8 KB
  __shared__ __align__(16) float4 sW2[8*32];   // 4 KB
  __shared__ float sG[256];
  __shared__ __align__(16) float sH[64];
  __shared__ __align__(16) float sM[64];
  __shared__ __align__(16) float sA1[32];
  __shared__ float sObs[16];
  __shared__ float sBuf[6];

  const int t    = threadIdx.x;
  const int blk  = blockIdx.x;
  const int lane = t & 63;
  const int wv0  = (t < 64);

  if (t < 64) out[BS*TS*2 + blk*64 + t] = 0.f;   // c_out zeros

  // one gate row per thread (64 VGPR)
  float4 wrow[16];
#pragma unroll
  for (int j=0;j<16;++j) wrow[j] = reinterpret_cast<const float4*>(Whh_o + t*64)[j];
  const float wi0  = Wih_o[2*t];
  const float wi1  = Wih_o[2*t+1];
  const float b_or = bih_o[t] + bhh_o[t];

  // wave0 MLP constants
  const int rr = lane & 31, half = lane >> 5;
  const float b1r  = b1[rr];
  const float b2r  = b2[rr];
  const float w3c0 = W3[rr];
  const float w3c1 = W3[32+rr];
  const float b3r  = b3[lane & 1];

  // staging (transposed-packed float4)
  for (int i=t;i<1024;i+=256) sWc[i] = reinterpret_cast<const float4*>(wcomb)[(i&63)*16 + (i>>6)];
  for (int i=t;i<512;i+=256)  sW1[i] = reinterpret_cast<const float4*>(W1)[(i&31)*16 + (i>>5)];
  if (t<256)                  sW2[t] = reinterpret_cast<const float4*>(W2)[(t&31)*8 + (t>>5)];
  if (t<16) sObs[t] = obsv[blk*16 + t];
  if (t<6)  sBuf[t] = obsv[blk*16 + 10 + t];
  if (t<64) sH[t] = 0.f;
  __syncthreads();

  float c_reg = 0.f;   // hidden-unit `lane` state (wave0)
  const float4* sH4  = reinterpret_cast<const float4*>(sH);
  const float4* sM4  = reinterpret_cast<const float4*>(sM);
  const float4* sA14 = reinterpret_cast<const float4*>(sA1);

  // ---- warmup: 8 obsv LSTM steps ----
  for (int s=0;s<8;++s){
    const float x0 = sObs[2*s], x1 = sObs[2*s+1];
    float a0 = b_or + wi0*x0 + wi1*x1, a1=0.f, a2=0.f, a3=0.f;
#pragma unroll
    for (int j=0;j<16;j+=4){
      a0 += dot4(wrow[j],   sH4[j]);
      a1 += dot4(wrow[j+1], sH4[j+1]);
      a2 += dot4(wrow[j+2], sH4[j+2]);
      a3 += dot4(wrow[j+3], sH4[j+3]);
    }
    sG[t] = (a0+a1)+(a2+a3);
    __syncthreads();
    if (wv0){
      float gi=sG[lane], gf=sG[64+lane], gg=sG[128+lane], go=sG[192+lane];
      c_reg = sigf(gf)*c_reg + sigf(gi)*tanh_fast(gg);
      sH[lane] = sigf(go)*tanh_fast(c_reg);
    }
    __syncthreads();
  }

  // ---- main loop: 64 output steps, 2 hard barriers/step ----
  for (int step=0; step<TS; ++step){
    float mb = 0.f;
    if (wv0) mb = mbias[step*64 + lane];   // prefetch under gate FMAs

    if (step>0){
      const float x0 = sBuf[4], x1 = sBuf[5];
      float a0 = b_or + wi0*x0 + wi1*x1, a1=0.f, a2=0.f, a3=0.f;
#pragma unroll
      for (int j=0;j<16;j+=4){
        a0 += dot4(wrow[j],   sH4[j]);
        a1 += dot4(wrow[j+1], sH4[j+1]);
        a2 += dot4(wrow[j+2], sH4[j+2]);
        a3 += dot4(wrow[j+3], sH4[j+3]);
      }
      sG[t] = (a0+a1)+(a2+a3);
    }
    __syncthreads();

    if (wv0){
      if (step>0){
        float gi=sG[lane], gf=sG[64+lane], gg=sG[128+lane], go=sG[192+lane];
        c_reg = sigf(gf)*c_reg + sigf(gi)*tanh_fast(gg);
        sH[lane] = sigf(go)*tanh_fast(c_reg);
        __builtin_amdgcn_wave_barrier();
      }
      // mix: m[lane] = Wcomb[lane,:] @ h + mbias
      float mix = mb;
#pragma unroll
      for (int j=0;j<16;++j) mix += dot4(sWc[j*64+lane], sH4[j]);
      sM[lane] = mix;
      __builtin_amdgcn_wave_barrier();
      // MLP1 (32x64), split-K halves
      float p1 = 0.f;
#pragma unroll
      for (int jj=0;jj<8;++jj) p1 += dot4(sW1[(half*8+jj)*32+rr], sM4[half*8+jj]);
      p1 += __shfl_xor(p1, 32);
      if (lane<32) sA1[lane] = lrelu(p1 + b1r);
      __builtin_amdgcn_wave_barrier();
      // MLP2 (32x32), split-K halves
      float p2 = 0.f;
#pragma unroll
      for (int jj=0;jj<4;++jj) p2 += dot4(sW2[(half*4+jj)*32+rr], sA14[half*4+jj]);
      p2 += __shfl_xor(p2, 32);
      const float a2v = lrelu(p2 + b2r);     // valid lanes<32
      // head (2x32): shuffle-tree over lanes 0..31
      float q0 = a2v*w3c0, q1 = a2v*w3c1;
#pragma unroll
      for (int m=1;m<=16;m<<=1){
        q0 += __shfl_xor(q0, m);
        q1 += __shfl_xor(q1, m);
      }
      if (lane<2){
        const float bl0 = sBuf[lane];
        const float bl1 = sBuf[2+lane];
        const float bl2 = sBuf[4+lane];
        const float y = ((lane==0)?q0:q1) + b3r + bl2 + (bl2-bl0)*0.5f;
        sBuf[lane]   = bl1;
        sBuf[2+lane] = bl2;
        sBuf[4+lane] = y;
        out[(size_t)(blk*TS+step)*2 + lane] = y;
      }
    }
    __syncthreads();
  }
}

extern "C" void kernel_launch(void* const* d_in, const int* in_sizes, int n_in,
                              void* d_out, int out_size, void* d_ws, size_t ws_size,
                              hipStream_t stream)
{
  const float* obsv  = (const float*)d_in[0];
  // d_in[1] = teom : never used (teom-LSTM input is zeros)
  const float* Wih_o = (const float*)d_in[2];
  const float* Whh_o = (const float*)d_in[3];
  const float* bih_o = (const float*)d_in[4];
  const float* bhh_o = (const float*)d_in[5];
  // d_in[6] = Wih_t : multiplies zeros, unused
  const float* Whh_t = (const float*)d_in[7];
  const float* bih_t = (const float*)d_in[8];
  const float* bhh_t = (const float*)d_in[9];
  const float* Wof   = (const float*)d_in[10];
  const float* bof   = (const float*)d_in[11];
  const float* Wtf   = (const float*)d_in[12];
  const float* btf   = (const float*)d_in[13];
  const float* Wmix  = (const float*)d_in[14];
  const float* bmix  = (const float*)d_in[15];
  const float* W1    = (const float*)d_in[16];
  const float* b1    = (const float*)d_in[17];
  const float* W2    = (const float*)d_in[18];
  const float* b2    = (const float*)d_in[19];
  const float* W3    = (const float*)d_in[20];
  const float* b3    = (const float*)d_in[21];

  float* wsf = (float*)d_ws;   // [0,4096): Wcomb   [4096,8192): mbias

  precompute_kernel<<<1,256,0,stream>>>(Whh_t,bih_t,bhh_t,Wof,bof,Wtf,btf,
                                        Wmix,bmix, wsf, wsf+4096);
  main_kernel<<<BS,256,0,stream>>>(obsv,Wih_o,Whh_o,bih_o,bhh_o,
                                   W1,b1,W2,b2,W3,b3,
                                   wsf, wsf+4096,
                                   (float*)d_out);
}